// Round 6
// baseline (382.751 us; speedup 1.0000x reference)
//
#include <hip/hip_runtime.h>
#include <math.h>

#define PP 4096   // P = H*W
#define CC 256    // channels
#define NN 2      // batch

typedef __attribute__((ext_vector_type(8))) short short8;
typedef __attribute__((ext_vector_type(4))) float f32x4;

__device__ __forceinline__ short f2bf(float x) {
    union { float f; unsigned u; } un; un.f = x;
    unsigned r = un.u + 0x7fffu + ((un.u >> 16) & 1u);  // RNE to bf16
    return (short)(r >> 16);
}

__device__ __forceinline__ void gld_lds16(const short* g, short* l) {
    __builtin_amdgcn_global_load_lds(
        (const __attribute__((address_space(1))) unsigned int*)g,
        (__attribute__((address_space(3))) unsigned int*)l, 16, 0, 0);
}

// ---- kernel 1: meanT[c] = mean over (n,p) of T; also init stats + ticket ----
__global__ __launch_bounds__(256) void mean_kernel(const float* __restrict__ T,
                                                   float* __restrict__ meanT,
                                                   unsigned* __restrict__ mn_enc,
                                                   float* __restrict__ S,
                                                   float* __restrict__ diagw,
                                                   unsigned* __restrict__ ticket) {
    int c = blockIdx.x, tid = threadIdx.x;
    float s = 0.f;
    for (int n = 0; n < NN; n++)
        for (int p = tid; p < PP; p += 256)
            s += T[(size_t)(n * CC + c) * PP + p];
    __shared__ float red[256];
    red[tid] = s; __syncthreads();
    for (int st = 128; st > 0; st >>= 1) {
        if (tid < st) red[tid] += red[tid + st];
        __syncthreads();
    }
    if (tid == 0) meanT[c] = red[0] * (1.0f / (NN * PP));
    // init stats: 256 blocks x 32 entries = NN*PP = 8192
    int base = blockIdx.x * 32;
    if (tid < 32) {
        mn_enc[base + tid] = 0xFFFFFFFFu;  // +inf in monotone-uint encoding
        S[base + tid] = 0.f;
        diagw[base + tid] = 0.f;
    }
    if (blockIdx.x == 0 && tid == 64) ticket[0] = 0u;
}

// ---- kernel 2: center by meanT, L2-normalize over C, write bf16 transposed [n][p][c] ----
__global__ __launch_bounds__(256) void normalize_kernel(const float* __restrict__ I,
                                                        const float* __restrict__ T,
                                                        const float* __restrict__ meanT,
                                                        short* __restrict__ InT,
                                                        short* __restrict__ TnT) {
    int pc = blockIdx.x * 32;      // 32 positions per block
    int n = blockIdx.y;
    int which = blockIdx.z;        // 0: I -> InT, 1: T -> TnT
    const float* X = which ? T : I;
    short* Y = which ? TnT : InT;

    __shared__ float tile[CC][33];   // [c][p_local], padded
    __shared__ float red[8][32];
    __shared__ float invn[32];

    int tid = threadIdx.x;
    int pl = tid & 31, c0 = tid >> 5;   // 8 c-groups x 32 p
    float sq = 0.f;
    for (int c = c0; c < CC; c += 8) {
        float v = X[(size_t)(n * CC + c) * PP + pc + pl] - meanT[c];
        tile[c][pl] = v;
        sq += v * v;
    }
    red[c0][pl] = sq;
    __syncthreads();
    if (tid < 32) {
        float s = 0.f;
        for (int k = 0; k < 8; k++) s += red[k][tid];
        invn[tid] = 1.0f / sqrtf(s);
    }
    __syncthreads();
    // vectorized write: 2 channels per thread, 2 rows per iteration (4B stores)
    for (int rr = 0; rr < 32; rr += 2) {
        int r = rr + (tid >> 7);
        int c2 = (tid & 127) * 2;
        float v0 = tile[c2][r] * invn[r];
        float v1 = tile[c2 + 1][r] * invn[r];
        unsigned pack = ((unsigned)(unsigned short)f2bf(v1) << 16) |
                        (unsigned)(unsigned short)f2bf(v0);
        *(unsigned*)&Y[(size_t)(n * PP + pc + r) * CC + c2] = pack;
    }
}

// ---- kernels 3/4: NT-GEMM dot[q,p] = sum_c TnT[q][c]*InT[p][c], fused col stats ----
// 128x128 tile, BK=32 DOUBLE-BUFFERED (one barrier/iter; vmcnt drain has a full
// compute phase of slack), 8 waves (each 32x64 via 2x4 16x16x32 MFMA, 32 AGPR acc).
// LDS 34 KB (2 x (8+8) KB + red) -> 3 blocks/CU at 6 waves/SIMD (launch_bounds 512,6).
// Swizzle: stored slot s of row r holds global chunk s^(r&3)^((r>>2)&3); read slot
// = quad^(lm&3)^(lm>>2) -> 2-way-max LDS granule aliasing (free) + 64B-contiguous
// global segments per 4 lanes.
// MODE 0: column (over q) min of raw=(1-dot)/2 -> atomicMin(mn_enc) [monotone uint]
// MODE 1: w = exp2(14.427 - raw*inv2); col sum -> atomicAdd(S); diag -> diagw;
//         last block (device ticket) computes the final loss.
template <int MODE>
__global__ __launch_bounds__(512, 6) void cx_gemm(const short* __restrict__ TnT,
                                                  const short* __restrict__ InT,
                                                  unsigned* __restrict__ mn_enc,
                                                  float* __restrict__ S,
                                                  float* __restrict__ diagw,
                                                  unsigned* __restrict__ ticket,
                                                  float* __restrict__ out) {
    const int n = blockIdx.z;
    const short* __restrict__ A = TnT + (size_t)n * PP * CC;  // A[q*CC + c]
    const short* __restrict__ B = InT + (size_t)n * PP * CC;  // B[p*CC + c]
    const int q0 = blockIdx.y * 128, p0 = blockIdx.x * 128;

    __shared__ __align__(16) short As[2][128 * 32];  // 8 KB x2
    __shared__ __align__(16) short Bs[2][128 * 32];  // 8 KB x2
    __shared__ float red[8][64];                     // 2 KB

    const int tid = threadIdx.x;
    const int l = tid & 63, wv = tid >> 6;
    const int lm = l & 15, quad = l >> 4;
    const int wr = (wv & 3) * 32, wc = (wv >> 2) * 64;  // wave tile: 32 rows x 64 cols

    // staging: srow = tid>>2 (0..127), slot = tid&3,
    // global chunk = slot ^ (srow&3) ^ ((srow>>2)&3); LDS dest lane-order (DMA rule)
    const int srow = tid >> 2;
    const int gchunk = (tid & 3) ^ (srow & 3) ^ ((srow >> 2) & 3);
    const short* Ag = A + (size_t)(q0 + srow) * CC + gchunk * 8;
    const short* Bg = B + (size_t)(p0 + srow) * CC + gchunk * 8;

    // read-side slot (row-independent across the fragment rows)
    const int rslot = (quad ^ (lm & 3) ^ (lm >> 2)) * 8;

    f32x4 acc[2][4] = {};

    // prologue: stage k-iter 0 into buffer 0
    gld_lds16(Ag, &As[0][tid * 8]);
    gld_lds16(Bg, &Bs[0][tid * 8]);

    for (int it = 0; it < 8; it++) {
        __syncthreads();  // drains vmcnt(0): stage(it) visible; prior buf reads done
        if (it < 7) {
            gld_lds16(Ag + (it + 1) * 32, &As[(it + 1) & 1][tid * 8]);
            gld_lds16(Bg + (it + 1) * 32, &Bs[(it + 1) & 1][tid * 8]);
        }
        const short* __restrict__ Asb = As[it & 1];
        const short* __restrict__ Bsb = Bs[it & 1];
        short8 a[2], b[4];
#pragma unroll
        for (int i = 0; i < 2; i++)
            a[i] = *(const short8*)&Asb[(wr + i * 16 + lm) * 32 + rslot];
#pragma unroll
        for (int j = 0; j < 4; j++)
            b[j] = *(const short8*)&Bsb[(wc + j * 16 + lm) * 32 + rslot];
#pragma unroll
        for (int i = 0; i < 2; i++)
#pragma unroll
            for (int j = 0; j < 4; j++)
                acc[i][j] = __builtin_amdgcn_mfma_f32_16x16x32_bf16(a[i], b[j], acc[i][j], 0, 0, 0);
    }

    // C/D layout: col = lm, row = quad*4 + reg (within each 16x16 tile)
    if (MODE == 0) {
#pragma unroll
        for (int j = 0; j < 4; j++) {
            float m = 3.4e38f;
#pragma unroll
            for (int i = 0; i < 2; i++)
#pragma unroll
                for (int e = 0; e < 4; e++)
                    m = fminf(m, (1.0f - acc[i][j][e]) * 0.5f);
            m = fminf(m, __shfl_xor(m, 16));
            m = fminf(m, __shfl_xor(m, 32));
            if (quad == 0) red[wv][j * 16 + lm] = m;  // wave's 32-row min, 64 cols
        }
        __syncthreads();
        if (tid < 128) {
            int grp = tid >> 6, idx = tid & 63;  // grp 0: waves 0-3; grp 1: waves 4-7
            float m = fminf(fminf(red[grp * 4 + 0][idx], red[grp * 4 + 1][idx]),
                            fminf(red[grp * 4 + 2][idx], red[grp * 4 + 3][idx]));
            unsigned u = __float_as_uint(m);
            u = (u & 0x80000000u) ? ~u : (u | 0x80000000u);  // monotone encoding
            atomicMin(&mn_enc[n * PP + p0 + tid], u);
        }
    } else {
#pragma unroll
        for (int j = 0; j < 4; j++) {
            const int col = p0 + wc + j * 16 + lm;  // global p
            unsigned e = mn_enc[n * PP + col];
            unsigned u = (e & 0x80000000u) ? (e & 0x7fffffffu) : ~e;  // decode
            float mnv = __uint_as_float(u);
            // w = exp(10 - 10*raw/(mn+eps)) = exp2(14.4269504 - raw*inv2)
            float inv2 = 14.4269504f / (mnv + 1e-5f);
            float s = 0.f;
#pragma unroll
            for (int i = 0; i < 2; i++)
#pragma unroll
                for (int e2 = 0; e2 < 4; e2++) {
                    float raw = (1.0f - acc[i][j][e2]) * 0.5f;
                    float w = exp2f(fmaf(raw, -inv2, 14.4269504f));
                    s += w;
                    int q = q0 + wr + i * 16 + quad * 4 + e2;  // global q
                    if (q == col) diagw[n * PP + q] = w;       // unique writer
                }
            s += __shfl_xor(s, 16);
            s += __shfl_xor(s, 32);
            if (quad == 0) red[wv][j * 16 + lm] = s;
        }
        __syncthreads();
        if (tid < 128) {
            int grp = tid >> 6, idx = tid & 63;
            float s = red[grp * 4 + 0][idx] + red[grp * 4 + 1][idx] +
                      red[grp * 4 + 2][idx] + red[grp * 4 + 3][idx];
            atomicAdd(&S[n * PP + p0 + tid], s);
        }

        // ---- fused finalize: last of gridDim.x*gridDim.y*NN blocks ----
        __shared__ unsigned rank_s;
        __threadfence();  // publish diagw stores + S atomics (device scope)
        __syncthreads();
        if (tid == 0) rank_s = atomicAdd(ticket, 1u);
        __syncthreads();
        if (rank_s == 32 * 32 * NN - 1) {
            __threadfence();  // acquire all other blocks' writes
            float s0 = 0.f, s1 = 0.f;
            for (int i = tid; i < PP; i += 512) {
                s0 += diagw[i] / S[i];
                s1 += diagw[PP + i] / S[PP + i];
            }
#pragma unroll
            for (int off = 32; off > 0; off >>= 1) {
                s0 += __shfl_xor(s0, off);
                s1 += __shfl_xor(s1, off);
            }
            if (l == 0) { red[0][wv] = s0; red[1][wv] = s1; }
            __syncthreads();
            if (tid == 0) {
                float t0 = 0.f, t1 = 0.f;
                for (int k = 0; k < 8; k++) { t0 += red[0][k]; t1 += red[1][k]; }
                float m0 = 0.5f + 0.5f * (t0 / (float)PP);
                float m1 = 0.5f + 0.5f * (t1 / (float)PP);
                out[0] = -0.5f * (logf(m0) + logf(m1));
            }
        }
    }
}

extern "C" void kernel_launch(void* const* d_in, const int* in_sizes, int n_in,
                              void* d_out, int out_size, void* d_ws, size_t ws_size,
                              hipStream_t stream) {
    const float* I = (const float*)d_in[0];
    const float* T = (const float*)d_in[1];
    float* out = (float*)d_out;

    char* ws = (char*)d_ws;
    const size_t SZ_BF = (size_t)NN * PP * CC * sizeof(short);  // 4 MB each
    short* InT = (short*)ws;
    short* TnT = (short*)(ws + SZ_BF);
    float* meanT = (float*)(ws + 2 * SZ_BF);               // 1 KB
    unsigned* mn = (unsigned*)(ws + 2 * SZ_BF + 32768);    // 32 KB
    float* S = (float*)(ws + 2 * SZ_BF + 2 * 32768);       // 32 KB
    float* diagw = (float*)(ws + 2 * SZ_BF + 3 * 32768);   // 32 KB
    unsigned* ticket = (unsigned*)(ws + 2 * SZ_BF + 4 * 32768);

    mean_kernel<<<CC, 256, 0, stream>>>(T, meanT, mn, S, diagw, ticket);
    normalize_kernel<<<dim3(PP / 32, NN, 2), 256, 0, stream>>>(I, T, meanT, InT, TnT);
    cx_gemm<0><<<dim3(PP / 128, PP / 128, NN), 512, 0, stream>>>(TnT, InT, mn, S, diagw, ticket, out);
    cx_gemm<1><<<dim3(PP / 128, PP / 128, NN), 512, 0, stream>>>(TnT, InT, mn, S, diagw, ticket, out);
}

// Round 7
// 382.084 us; speedup vs baseline: 1.0017x; 1.0017x over previous
//
#include <hip/hip_runtime.h>
#include <math.h>

#define PP 4096   // P = H*W
#define CC 256    // channels
#define NN 2      // batch

typedef __attribute__((ext_vector_type(8))) short short8;
typedef __attribute__((ext_vector_type(4))) float f32x4;

__device__ __forceinline__ short f2bf(float x) {
    union { float f; unsigned u; } un; un.f = x;
    unsigned r = un.u + 0x7fffu + ((un.u >> 16) & 1u);  // RNE to bf16
    return (short)(r >> 16);
}

__device__ __forceinline__ void gld_lds16(const short* g, short* l) {
    __builtin_amdgcn_global_load_lds(
        (const __attribute__((address_space(1))) unsigned int*)g,
        (__attribute__((address_space(3))) unsigned int*)l, 16, 0, 0);
}

// ---- kernel 1: meanT[c] = mean over (n,p) of T; also init stats + ticket ----
__global__ __launch_bounds__(256) void mean_kernel(const float* __restrict__ T,
                                                   float* __restrict__ meanT,
                                                   unsigned* __restrict__ mn_enc,
                                                   float* __restrict__ S,
                                                   float* __restrict__ diagw,
                                                   unsigned* __restrict__ ticket) {
    int c = blockIdx.x, tid = threadIdx.x;
    float s = 0.f;
    for (int n = 0; n < NN; n++)
        for (int p = tid; p < PP; p += 256)
            s += T[(size_t)(n * CC + c) * PP + p];
    __shared__ float red[256];
    red[tid] = s; __syncthreads();
    for (int st = 128; st > 0; st >>= 1) {
        if (tid < st) red[tid] += red[tid + st];
        __syncthreads();
    }
    if (tid == 0) meanT[c] = red[0] * (1.0f / (NN * PP));
    // init stats: 256 blocks x 32 entries = NN*PP = 8192
    int base = blockIdx.x * 32;
    if (tid < 32) {
        mn_enc[base + tid] = 0xFFFFFFFFu;  // +inf in monotone-uint encoding
        S[base + tid] = 0.f;
        diagw[base + tid] = 0.f;
    }
    if (blockIdx.x == 0 && tid == 64) ticket[0] = 0u;
}

// ---- kernel 2: center by meanT, L2-normalize over C, write bf16 transposed [n][p][c] ----
__global__ __launch_bounds__(256) void normalize_kernel(const float* __restrict__ I,
                                                        const float* __restrict__ T,
                                                        const float* __restrict__ meanT,
                                                        short* __restrict__ InT,
                                                        short* __restrict__ TnT) {
    int pc = blockIdx.x * 32;      // 32 positions per block
    int n = blockIdx.y;
    int which = blockIdx.z;        // 0: I -> InT, 1: T -> TnT
    const float* X = which ? T : I;
    short* Y = which ? TnT : InT;

    __shared__ float tile[CC][33];   // [c][p_local], padded
    __shared__ float red[8][32];
    __shared__ float invn[32];

    int tid = threadIdx.x;
    int pl = tid & 31, c0 = tid >> 5;   // 8 c-groups x 32 p
    float sq = 0.f;
    for (int c = c0; c < CC; c += 8) {
        float v = X[(size_t)(n * CC + c) * PP + pc + pl] - meanT[c];
        tile[c][pl] = v;
        sq += v * v;
    }
    red[c0][pl] = sq;
    __syncthreads();
    if (tid < 32) {
        float s = 0.f;
        for (int k = 0; k < 8; k++) s += red[k][tid];
        invn[tid] = 1.0f / sqrtf(s);
    }
    __syncthreads();
    // vectorized write: 2 channels per thread, 2 rows per iteration (4B stores)
    for (int rr = 0; rr < 32; rr += 2) {
        int r = rr + (tid >> 7);
        int c2 = (tid & 127) * 2;
        float v0 = tile[c2][r] * invn[r];
        float v1 = tile[c2 + 1][r] * invn[r];
        unsigned pack = ((unsigned)(unsigned short)f2bf(v1) << 16) |
                        (unsigned)(unsigned short)f2bf(v0);
        *(unsigned*)&Y[(size_t)(n * PP + pc + r) * CC + c2] = pack;
    }
}

// ---- kernels 3/4: NT-GEMM dot[q,p] = sum_c TnT[q][c]*InT[p][c], fused col stats ----
// ROUND-5 STRUCTURE (known good): 128x128 tile, BK=64 single-buffer, 8 waves
// (each 32x64 via 2x4 16x16x32 MFMA, 32 AGPR acc), launch_bounds(512,6),
// LDS 34 KB -> 3 blocks/CU. global_load_lds 16B staging, XOR swizzle
// (slot s of row r holds chunk s^(r&7)): coalesced 128B segments, 0 conflicts.
// [journal r6: BK=32 dbuf with dynamic buffer indices regressed 10x — compiler
//  dropped fragment registers (VGPR 36) and serialized ds_read->MFMA; do NOT
//  revisit explicit dbuf on this structure.]
// MODE 0: column (over q) min of raw=(1-dot)/2 -> atomicMin(mn_enc) [monotone uint]
// MODE 1: w = exp2(14.427 - raw*inv2); col sum -> atomicAdd(S); diag -> diagw;
//         last block (device ticket) computes the final loss.
template <int MODE>
__global__ __launch_bounds__(512, 6) void cx_gemm(const short* __restrict__ TnT,
                                                  const short* __restrict__ InT,
                                                  unsigned* __restrict__ mn_enc,
                                                  float* __restrict__ S,
                                                  float* __restrict__ diagw,
                                                  unsigned* __restrict__ ticket,
                                                  float* __restrict__ out) {
    const int n = blockIdx.z;
    const short* __restrict__ A = TnT + (size_t)n * PP * CC;  // A[q*CC + c]
    const short* __restrict__ B = InT + (size_t)n * PP * CC;  // B[p*CC + c]
    const int q0 = blockIdx.y * 128, p0 = blockIdx.x * 128;

    __shared__ __align__(16) short As[128 * 64];  // 16 KB
    __shared__ __align__(16) short Bs[128 * 64];  // 16 KB
    __shared__ float red[8][64];                  // 2 KB

    const int tid = threadIdx.x;
    const int l = tid & 63, wv = tid >> 6;
    const int lm = l & 15, quad = l >> 4;
    const int wr = (wv & 3) * 32, wc = (wv >> 2) * 64;  // wave tile: 32 rows x 64 cols

    // staging: issue t covers rows t*64 + (tid>>3), slot tid&7;
    // global chunk = slot ^ (row&7); LDS dest lane-order contiguous (DMA rule)
    const int srow = tid >> 3;                       // 0..63
    const int gk = ((tid & 7) ^ (srow & 7)) * 8;     // (row+64)&7 == row&7
    const short* Ag = A + (size_t)(q0 + srow) * CC + gk;
    const short* Bg = B + (size_t)(p0 + srow) * CC + gk;
    short* Al = As + tid * 8;
    short* Bl = Bs + tid * 8;

    f32x4 acc[2][4] = {};

    for (int k0 = 0; k0 < CC; k0 += 64) {
        __syncthreads();  // previous iter's LDS reads done
        gld_lds16(Ag + k0, Al);
        gld_lds16(Ag + 64 * CC + k0, Al + 4096);
        gld_lds16(Bg + k0, Bl);
        gld_lds16(Bg + 64 * CC + k0, Bl + 4096);
        __syncthreads();  // drains vmcnt(0): staged data visible

#pragma unroll
        for (int ksub = 0; ksub < 2; ksub++) {
            const int c = ksub * 4 + quad;  // logical 8-elem k-chunk
            short8 a[2], b[4];
#pragma unroll
            for (int i = 0; i < 2; i++)
                a[i] = *(const short8*)&As[(wr + i * 16 + lm) * 64 + (c ^ (lm & 7)) * 8];
#pragma unroll
            for (int j = 0; j < 4; j++)
                b[j] = *(const short8*)&Bs[(wc + j * 16 + lm) * 64 + (c ^ (lm & 7)) * 8];
#pragma unroll
            for (int i = 0; i < 2; i++)
#pragma unroll
                for (int j = 0; j < 4; j++)
                    acc[i][j] = __builtin_amdgcn_mfma_f32_16x16x32_bf16(a[i], b[j], acc[i][j], 0, 0, 0);
        }
    }

    // C/D layout: col = lm, row = quad*4 + reg (within each 16x16 tile)
    if (MODE == 0) {
#pragma unroll
        for (int j = 0; j < 4; j++) {
            float m = 3.4e38f;
#pragma unroll
            for (int i = 0; i < 2; i++)
#pragma unroll
                for (int e = 0; e < 4; e++)
                    m = fminf(m, (1.0f - acc[i][j][e]) * 0.5f);
            m = fminf(m, __shfl_xor(m, 16));
            m = fminf(m, __shfl_xor(m, 32));
            if (quad == 0) red[wv][j * 16 + lm] = m;  // wave's 32-row min, 64 cols
        }
        __syncthreads();
        if (tid < 128) {
            int grp = tid >> 6, idx = tid & 63;  // grp 0: waves 0-3; grp 1: waves 4-7
            float m = fminf(fminf(red[grp * 4 + 0][idx], red[grp * 4 + 1][idx]),
                            fminf(red[grp * 4 + 2][idx], red[grp * 4 + 3][idx]));
            unsigned u = __float_as_uint(m);
            u = (u & 0x80000000u) ? ~u : (u | 0x80000000u);  // monotone encoding
            atomicMin(&mn_enc[n * PP + p0 + tid], u);
        }
    } else {
#pragma unroll
        for (int j = 0; j < 4; j++) {
            const int col = p0 + wc + j * 16 + lm;  // global p
            unsigned e = mn_enc[n * PP + col];
            unsigned u = (e & 0x80000000u) ? (e & 0x7fffffffu) : ~e;  // decode
            float mnv = __uint_as_float(u);
            // w = exp(10 - 10*raw/(mn+eps)) = exp2(14.4269504 - raw*inv2)
            float inv2 = 14.4269504f / (mnv + 1e-5f);
            float s = 0.f;
#pragma unroll
            for (int i = 0; i < 2; i++)
#pragma unroll
                for (int e2 = 0; e2 < 4; e2++) {
                    float raw = (1.0f - acc[i][j][e2]) * 0.5f;
                    float w = exp2f(fmaf(raw, -inv2, 14.4269504f));
                    s += w;
                    int q = q0 + wr + i * 16 + quad * 4 + e2;  // global q
                    if (q == col) diagw[n * PP + q] = w;       // unique writer
                }
            s += __shfl_xor(s, 16);
            s += __shfl_xor(s, 32);
            if (quad == 0) red[wv][j * 16 + lm] = s;
        }
        __syncthreads();
        if (tid < 128) {
            int grp = tid >> 6, idx = tid & 63;
            float s = red[grp * 4 + 0][idx] + red[grp * 4 + 1][idx] +
                      red[grp * 4 + 2][idx] + red[grp * 4 + 3][idx];
            atomicAdd(&S[n * PP + p0 + tid], s);
        }

        // ---- fused finalize: last of 32*32*NN blocks reduces the loss ----
        __shared__ unsigned rank_s;
        __threadfence();  // publish diagw stores + S atomics (device scope)
        __syncthreads();
        if (tid == 0) rank_s = atomicAdd(ticket, 1u);
        __syncthreads();
        if (rank_s == 32 * 32 * NN - 1) {
            __threadfence();  // acquire all other blocks' writes
            float s0 = 0.f, s1 = 0.f;
            for (int i = tid; i < PP; i += 512) {
                s0 += diagw[i] / S[i];
                s1 += diagw[PP + i] / S[PP + i];
            }
#pragma unroll
            for (int off = 32; off > 0; off >>= 1) {
                s0 += __shfl_xor(s0, off);
                s1 += __shfl_xor(s1, off);
            }
            if (l == 0) { red[0][wv] = s0; red[1][wv] = s1; }
            __syncthreads();
            if (tid == 0) {
                float t0 = 0.f, t1 = 0.f;
                for (int k = 0; k < 8; k++) { t0 += red[0][k]; t1 += red[1][k]; }
                float m0 = 0.5f + 0.5f * (t0 / (float)PP);
                float m1 = 0.5f + 0.5f * (t1 / (float)PP);
                out[0] = -0.5f * (logf(m0) + logf(m1));
            }
        }
    }
}

extern "C" void kernel_launch(void* const* d_in, const int* in_sizes, int n_in,
                              void* d_out, int out_size, void* d_ws, size_t ws_size,
                              hipStream_t stream) {
    const float* I = (const float*)d_in[0];
    const float* T = (const float*)d_in[1];
    float* out = (float*)d_out;

    char* ws = (char*)d_ws;
    const size_t SZ_BF = (size_t)NN * PP * CC * sizeof(short);  // 4 MB each
    short* InT = (short*)ws;
    short* TnT = (short*)(ws + SZ_BF);
    float* meanT = (float*)(ws + 2 * SZ_BF);               // 1 KB
    unsigned* mn = (unsigned*)(ws + 2 * SZ_BF + 32768);    // 32 KB
    float* S = (float*)(ws + 2 * SZ_BF + 2 * 32768);       // 32 KB
    float* diagw = (float*)(ws + 2 * SZ_BF + 3 * 32768);   // 32 KB
    unsigned* ticket = (unsigned*)(ws + 2 * SZ_BF + 4 * 32768);

    mean_kernel<<<CC, 256, 0, stream>>>(T, meanT, mn, S, diagw, ticket);
    normalize_kernel<<<dim3(PP / 32, NN, 2), 256, 0, stream>>>(I, T, meanT, InT, TnT);
    cx_gemm<0><<<dim3(PP / 128, PP / 128, NN), 512, 0, stream>>>(TnT, InT, mn, S, diagw, ticket, out);
    cx_gemm<1><<<dim3(PP / 128, PP / 128, NN), 512, 0, stream>>>(TnT, InT, mn, S, diagw, ticket, out);
}

// Round 8
// 130.729 us; speedup vs baseline: 2.9278x; 2.9227x over previous
//
#include <hip/hip_runtime.h>
#include <math.h>

#define PP 4096   // P = H*W
#define CC 256    // channels
#define NN 2      // batch

typedef __attribute__((ext_vector_type(8))) short short8;
typedef __attribute__((ext_vector_type(4))) float f32x4;

__device__ __forceinline__ short f2bf(float x) {
    union { float f; unsigned u; } un; un.f = x;
    unsigned r = un.u + 0x7fffu + ((un.u >> 16) & 1u);  // RNE to bf16
    return (short)(r >> 16);
}

__device__ __forceinline__ void gld_lds16(const short* g, short* l) {
    __builtin_amdgcn_global_load_lds(
        (const __attribute__((address_space(1))) unsigned int*)g,
        (__attribute__((address_space(3))) unsigned int*)l, 16, 0, 0);
}

// ---- kernel 1: meanT[c] = mean over (n,p) of T; also init stats arrays ----
__global__ __launch_bounds__(256) void mean_kernel(const float* __restrict__ T,
                                                   float* __restrict__ meanT,
                                                   unsigned* __restrict__ mn_enc,
                                                   float* __restrict__ S,
                                                   float* __restrict__ diagw) {
    int c = blockIdx.x, tid = threadIdx.x;
    float s = 0.f;
    for (int n = 0; n < NN; n++)
        for (int p = tid; p < PP; p += 256)
            s += T[(size_t)(n * CC + c) * PP + p];
    __shared__ float red[256];
    red[tid] = s; __syncthreads();
    for (int st = 128; st > 0; st >>= 1) {
        if (tid < st) red[tid] += red[tid + st];
        __syncthreads();
    }
    if (tid == 0) meanT[c] = red[0] * (1.0f / (NN * PP));
    // init stats: 256 blocks x 32 entries = NN*PP = 8192
    int base = blockIdx.x * 32;
    if (tid < 32) {
        mn_enc[base + tid] = 0xFFFFFFFFu;  // +inf in monotone-uint encoding
        S[base + tid] = 0.f;
        diagw[base + tid] = 0.f;
    }
}

// ---- kernel 2: center by meanT, L2-normalize over C, write bf16 transposed [n][p][c] ----
__global__ __launch_bounds__(256) void normalize_kernel(const float* __restrict__ I,
                                                        const float* __restrict__ T,
                                                        const float* __restrict__ meanT,
                                                        short* __restrict__ InT,
                                                        short* __restrict__ TnT) {
    int pc = blockIdx.x * 32;      // 32 positions per block
    int n = blockIdx.y;
    int which = blockIdx.z;        // 0: I -> InT, 1: T -> TnT
    const float* X = which ? T : I;
    short* Y = which ? TnT : InT;

    __shared__ float tile[CC][33];   // [c][p_local], padded
    __shared__ float red[8][32];
    __shared__ float invn[32];

    int tid = threadIdx.x;
    int pl = tid & 31, c0 = tid >> 5;   // 8 c-groups x 32 p
    float sq = 0.f;
    for (int c = c0; c < CC; c += 8) {
        float v = X[(size_t)(n * CC + c) * PP + pc + pl] - meanT[c];
        tile[c][pl] = v;
        sq += v * v;
    }
    red[c0][pl] = sq;
    __syncthreads();
    if (tid < 32) {
        float s = 0.f;
        for (int k = 0; k < 8; k++) s += red[k][tid];
        invn[tid] = 1.0f / sqrtf(s);
    }
    __syncthreads();
    // vectorized write: 2 channels per thread, 2 rows per iteration (4B stores)
    for (int rr = 0; rr < 32; rr += 2) {
        int r = rr + (tid >> 7);
        int c2 = (tid & 127) * 2;
        float v0 = tile[c2][r] * invn[r];
        float v1 = tile[c2 + 1][r] * invn[r];
        unsigned pack = ((unsigned)(unsigned short)f2bf(v1) << 16) |
                        (unsigned)(unsigned short)f2bf(v0);
        *(unsigned*)&Y[(size_t)(n * PP + pc + r) * CC + c2] = pack;
    }
}

// ---- kernels 3/4: NT-GEMM dot[q,p] = sum_c TnT[q][c]*InT[p][c], fused col stats ----
// ROUND-5 STRUCTURE VERBATIM (known good, 130.4 us total): 128x128 tile, BK=64
// single-buffer, 8 waves (32x64 each via 2x4 16x16x32 MFMA, 32 AGPR acc),
// launch_bounds(512,6), LDS 34 KB. global_load_lds 16B staging, XOR swizzle
// (slot s of row r holds chunk s^(r&7)): coalesced 128B segments, 0 conflicts.
// [journal r6/r7: the 10x regression was NOT the dbuf k-loop — it was the
//  ticket-fused finalize's per-block device-scope __threadfence (L2 writeback
//  storm across 2048 blocks). NEVER put a device fence in a hot epilogue.
//  Keep finalize as its own tiny launch.]
// MODE 0: column (over q) min of raw=(1-dot)/2 -> atomicMin(mn_enc) [monotone uint]
// MODE 1: w = exp2(14.427 - raw*inv2); col sum -> atomicAdd(S); diag -> diagw
template <int MODE>
__global__ __launch_bounds__(512, 6) void cx_gemm(const short* __restrict__ TnT,
                                                  const short* __restrict__ InT,
                                                  unsigned* __restrict__ mn_enc,
                                                  float* __restrict__ S,
                                                  float* __restrict__ diagw) {
    const int n = blockIdx.z;
    const short* __restrict__ A = TnT + (size_t)n * PP * CC;  // A[q*CC + c]
    const short* __restrict__ B = InT + (size_t)n * PP * CC;  // B[p*CC + c]
    const int q0 = blockIdx.y * 128, p0 = blockIdx.x * 128;

    __shared__ __align__(16) short As[128 * 64];  // 16 KB
    __shared__ __align__(16) short Bs[128 * 64];  // 16 KB
    __shared__ float red[8][64];                  // 2 KB

    const int tid = threadIdx.x;
    const int l = tid & 63, wv = tid >> 6;
    const int lm = l & 15, quad = l >> 4;
    const int wr = (wv & 3) * 32, wc = (wv >> 2) * 64;  // wave tile: 32 rows x 64 cols

    // staging: issue t covers rows t*64 + (tid>>3), slot tid&7;
    // global chunk = slot ^ (row&7); LDS dest lane-order contiguous (DMA rule)
    const int srow = tid >> 3;                       // 0..63
    const int gk = ((tid & 7) ^ (srow & 7)) * 8;     // (row+64)&7 == row&7
    const short* Ag = A + (size_t)(q0 + srow) * CC + gk;
    const short* Bg = B + (size_t)(p0 + srow) * CC + gk;
    short* Al = As + tid * 8;
    short* Bl = Bs + tid * 8;

    f32x4 acc[2][4] = {};

    for (int k0 = 0; k0 < CC; k0 += 64) {
        __syncthreads();  // previous iter's LDS reads done
        gld_lds16(Ag + k0, Al);
        gld_lds16(Ag + 64 * CC + k0, Al + 4096);
        gld_lds16(Bg + k0, Bl);
        gld_lds16(Bg + 64 * CC + k0, Bl + 4096);
        __syncthreads();  // drains vmcnt(0): staged data visible

#pragma unroll
        for (int ksub = 0; ksub < 2; ksub++) {
            const int c = ksub * 4 + quad;  // logical 8-elem k-chunk
            short8 a[2], b[4];
#pragma unroll
            for (int i = 0; i < 2; i++)
                a[i] = *(const short8*)&As[(wr + i * 16 + lm) * 64 + (c ^ (lm & 7)) * 8];
#pragma unroll
            for (int j = 0; j < 4; j++)
                b[j] = *(const short8*)&Bs[(wc + j * 16 + lm) * 64 + (c ^ (lm & 7)) * 8];
#pragma unroll
            for (int i = 0; i < 2; i++)
#pragma unroll
                for (int j = 0; j < 4; j++)
                    acc[i][j] = __builtin_amdgcn_mfma_f32_16x16x32_bf16(a[i], b[j], acc[i][j], 0, 0, 0);
        }
    }

    // C/D layout: col = lm, row = quad*4 + reg (within each 16x16 tile)
    if (MODE == 0) {
#pragma unroll
        for (int j = 0; j < 4; j++) {
            float m = 3.4e38f;
#pragma unroll
            for (int i = 0; i < 2; i++)
#pragma unroll
                for (int e = 0; e < 4; e++)
                    m = fminf(m, (1.0f - acc[i][j][e]) * 0.5f);
            m = fminf(m, __shfl_xor(m, 16));
            m = fminf(m, __shfl_xor(m, 32));
            if (quad == 0) red[wv][j * 16 + lm] = m;  // wave's 32-row min, 64 cols
        }
        __syncthreads();
        if (tid < 128) {
            int grp = tid >> 6, idx = tid & 63;  // grp 0: waves 0-3; grp 1: waves 4-7
            float m = fminf(fminf(red[grp * 4 + 0][idx], red[grp * 4 + 1][idx]),
                            fminf(red[grp * 4 + 2][idx], red[grp * 4 + 3][idx]));
            unsigned u = __float_as_uint(m);
            u = (u & 0x80000000u) ? ~u : (u | 0x80000000u);  // monotone encoding
            atomicMin(&mn_enc[n * PP + p0 + tid], u);
        }
    } else {
#pragma unroll
        for (int j = 0; j < 4; j++) {
            const int col = p0 + wc + j * 16 + lm;  // global p
            unsigned e = mn_enc[n * PP + col];
            unsigned u = (e & 0x80000000u) ? (e & 0x7fffffffu) : ~e;  // decode
            float mnv = __uint_as_float(u);
            // w = exp(10 - 10*raw/(mn+eps)) = exp2(14.4269504 - raw*inv2)
            float inv2 = 14.4269504f / (mnv + 1e-5f);
            float s = 0.f;
#pragma unroll
            for (int i = 0; i < 2; i++)
#pragma unroll
                for (int e2 = 0; e2 < 4; e2++) {
                    float raw = (1.0f - acc[i][j][e2]) * 0.5f;
                    float w = exp2f(fmaf(raw, -inv2, 14.4269504f));
                    s += w;
                    int q = q0 + wr + i * 16 + quad * 4 + e2;  // global q
                    if (q == col) diagw[n * PP + q] = w;       // unique writer
                }
            s += __shfl_xor(s, 16);
            s += __shfl_xor(s, 32);
            if (quad == 0) red[wv][j * 16 + lm] = s;
        }
        __syncthreads();
        if (tid < 128) {
            int grp = tid >> 6, idx = tid & 63;
            float s = red[grp * 4 + 0][idx] + red[grp * 4 + 1][idx] +
                      red[grp * 4 + 2][idx] + red[grp * 4 + 3][idx];
            atomicAdd(&S[n * PP + p0 + tid], s);
        }
    }
}

// ---- kernel 5: loss = mean_n -log(0.5 + 0.5 * mean_q(diagw/S)); n parallel ----
__global__ __launch_bounds__(1024) void finalize_kernel(const float* __restrict__ S,
                                                        const float* __restrict__ diagw,
                                                        float* __restrict__ out) {
    __shared__ float red[1024];
    int tid = threadIdx.x;
    int n = tid >> 9, t = tid & 511;
    float s = 0.f;
    for (int i = t; i < PP; i += 512)
        s += diagw[n * PP + i] / S[n * PP + i];
    red[tid] = s; __syncthreads();
    for (int st = 256; st > 0; st >>= 1) {
        if (t < st) red[n * 512 + t] += red[n * 512 + t + st];
        __syncthreads();
    }
    if (tid == 0) {
        float m0 = 0.5f + 0.5f * (red[0] / (float)PP);
        float m1 = 0.5f + 0.5f * (red[512] / (float)PP);
        out[0] = 0.5f * (-logf(m0) - logf(m1));
    }
}

extern "C" void kernel_launch(void* const* d_in, const int* in_sizes, int n_in,
                              void* d_out, int out_size, void* d_ws, size_t ws_size,
                              hipStream_t stream) {
    const float* I = (const float*)d_in[0];
    const float* T = (const float*)d_in[1];
    float* out = (float*)d_out;

    char* ws = (char*)d_ws;
    const size_t SZ_BF = (size_t)NN * PP * CC * sizeof(short);  // 4 MB each
    short* InT = (short*)ws;
    short* TnT = (short*)(ws + SZ_BF);
    float* meanT = (float*)(ws + 2 * SZ_BF);               // 1 KB
    unsigned* mn = (unsigned*)(ws + 2 * SZ_BF + 32768);    // 32 KB
    float* S = (float*)(ws + 2 * SZ_BF + 2 * 32768);       // 32 KB
    float* diagw = (float*)(ws + 2 * SZ_BF + 3 * 32768);   // 32 KB

    mean_kernel<<<CC, 256, 0, stream>>>(T, meanT, mn, S, diagw);
    normalize_kernel<<<dim3(PP / 32, NN, 2), 256, 0, stream>>>(I, T, meanT, InT, TnT);
    cx_gemm<0><<<dim3(PP / 128, PP / 128, NN), 512, 0, stream>>>(TnT, InT, mn, S, diagw);
    cx_gemm<1><<<dim3(PP / 128, PP / 128, NN), 512, 0, stream>>>(TnT, InT, mn, S, diagw);
    finalize_kernel<<<1, 1024, 0, stream>>>(S, diagw, out);
}

// Round 9
// 127.290 us; speedup vs baseline: 3.0069x; 1.0270x over previous
//
#include <hip/hip_runtime.h>
#include <math.h>

#define PP 4096   // P = H*W
#define CC 256    // channels
#define NN 2      // batch

typedef __attribute__((ext_vector_type(4))) float f32x4;

__device__ __forceinline__ void gld_lds16(const char* g, char* l) {
    __builtin_amdgcn_global_load_lds(
        (const __attribute__((address_space(1))) unsigned int*)g,
        (__attribute__((address_space(3))) unsigned int*)l, 16, 0, 0);
}

// ---- kernel 1: meanT[c] = mean over (n,p) of T; also init stats arrays ----
__global__ __launch_bounds__(256) void mean_kernel(const float* __restrict__ T,
                                                   float* __restrict__ meanT,
                                                   unsigned* __restrict__ mn_enc,
                                                   float* __restrict__ S,
                                                   float* __restrict__ diagw) {
    int c = blockIdx.x, tid = threadIdx.x;
    float s = 0.f;
    for (int n = 0; n < NN; n++)
        for (int p = tid; p < PP; p += 256)
            s += T[(size_t)(n * CC + c) * PP + p];
    __shared__ float red[256];
    red[tid] = s; __syncthreads();
    for (int st = 128; st > 0; st >>= 1) {
        if (tid < st) red[tid] += red[tid + st];
        __syncthreads();
    }
    if (tid == 0) meanT[c] = red[0] * (1.0f / (NN * PP));
    // init stats: 256 blocks x 32 entries = NN*PP = 8192
    int base = blockIdx.x * 32;
    if (tid < 32) {
        mn_enc[base + tid] = 0xFFFFFFFFu;  // +inf in monotone-uint encoding
        S[base + tid] = 0.f;
        diagw[base + tid] = 0.f;
    }
}

// ---- kernel 2: center by meanT, L2-normalize over C, write FP8 e4m3 [n][p][c] ----
__global__ __launch_bounds__(256) void normalize_kernel(const float* __restrict__ I,
                                                        const float* __restrict__ T,
                                                        const float* __restrict__ meanT,
                                                        char* __restrict__ InT,
                                                        char* __restrict__ TnT) {
    int pc = blockIdx.x * 32;      // 32 positions per block
    int n = blockIdx.y;
    int which = blockIdx.z;        // 0: I -> InT, 1: T -> TnT
    const float* X = which ? T : I;
    char* Y = which ? TnT : InT;

    __shared__ float tile[CC][33];   // [c][p_local], padded
    __shared__ float red[8][32];
    __shared__ float invn[32];

    int tid = threadIdx.x;
    int pl = tid & 31, c0 = tid >> 5;   // 8 c-groups x 32 p
    float sq = 0.f;
    for (int c = c0; c < CC; c += 8) {
        float v = X[(size_t)(n * CC + c) * PP + pc + pl] - meanT[c];
        tile[c][pl] = v;
        sq += v * v;
    }
    red[c0][pl] = sq;
    __syncthreads();
    if (tid < 32) {
        float s = 0.f;
        for (int k = 0; k < 8; k++) s += red[k][tid];
        invn[tid] = 1.0f / sqrtf(s);
    }
    __syncthreads();
    // write fp8: 4 channels per thread (4B store), 4 rows per pass, 8 passes
    for (int pass = 0; pass < 8; pass++) {
        int r = pass * 4 + (tid >> 6);
        int c4 = (tid & 63) * 4;
        float in = invn[r];
        float v0 = tile[c4 + 0][r] * in;
        float v1 = tile[c4 + 1][r] * in;
        float v2 = tile[c4 + 2][r] * in;
        float v3 = tile[c4 + 3][r] * in;
        int w = __builtin_amdgcn_cvt_pk_fp8_f32(v0, v1, 0, false);
        w = __builtin_amdgcn_cvt_pk_fp8_f32(v2, v3, w, true);
        *(unsigned*)&Y[(size_t)(n * PP + pc + r) * CC + c4] = (unsigned)w;
    }
}

// ---- kernels 3/4: FP8 NT-GEMM dot[q,p] = sum_c TnT[q][c]*InT[p][c] + col stats ----
// 128x128 tile, BK=128 (only TWO k-iters -> half the vmcnt barrier drains of the
// bf16 r5 version), 8 waves (32x64 each via 2x4 16x16x32_fp8_fp8 MFMA, 32 AGPR acc),
// launch_bounds(512,6), LDS 34 KB (16+16+2). global_load_lds 16B staging.
// Swizzle: stored 16B slot s of row r holds global chunk s^((r>>1)&7) (even in
// granule space -> DMA-compatible); read byte pos = (c ^ (lm&14))*8: even/odd lane
// pairs broadcast (free), banks fully spread otherwise.
// [journal r6/r7: NEVER put device-scope __threadfence in a hot epilogue -
//  L2 writeback storm, 10x. Finalize stays a separate tiny launch.]
// MODE 0: column (over q) min of raw=(1-dot)/2 -> atomicMin(mn_enc) [monotone uint]
// MODE 1: w = exp2(14.427 - raw*inv2); col sum -> atomicAdd(S); diag -> diagw
template <int MODE>
__global__ __launch_bounds__(512, 6) void cx_gemm(const char* __restrict__ TnT,
                                                  const char* __restrict__ InT,
                                                  unsigned* __restrict__ mn_enc,
                                                  float* __restrict__ S,
                                                  float* __restrict__ diagw) {
    const int n = blockIdx.z;
    const char* __restrict__ A = TnT + (size_t)n * PP * CC;  // A[q*CC + c], 1B/elem
    const char* __restrict__ B = InT + (size_t)n * PP * CC;  // B[p*CC + c]
    const int q0 = blockIdx.y * 128, p0 = blockIdx.x * 128;

    __shared__ __align__(16) char As[128 * 128];  // 16 KB
    __shared__ __align__(16) char Bs[128 * 128];  // 16 KB
    __shared__ float red[8][64];                  // 2 KB

    const int tid = threadIdx.x;
    const int l = tid & 63, wv = tid >> 6;
    const int lm = l & 15, quad = l >> 4;
    const int wr = (wv & 3) * 32, wc = (wv >> 2) * 64;  // wave tile: 32 rows x 64 cols

    // staging: issue t covers rows t*64 + (tid>>3), 16B slot tid&7;
    // global chunk16 = slot ^ ((row>>1)&7); LDS dest lane-order contiguous (DMA)
    const int srow = tid >> 3;                        // 0..63
    const int gk = ((tid & 7) ^ ((srow >> 1) & 7)) * 16;  // (row+64)>>1 &7 == same
    const char* Ag = A + (size_t)(q0 + srow) * CC + gk;
    const char* Bg = B + (size_t)(p0 + srow) * CC + gk;
    char* Al = As + tid * 16;
    char* Bl = Bs + tid * 16;

    f32x4 acc[2][4] = {};

    const int rsw = (lm & 14);  // read-side granule XOR (row&14 == lm&14)

#pragma unroll
    for (int it = 0; it < 2; it++) {
        __syncthreads();  // previous iter's LDS reads done
        gld_lds16(Ag + it * 128, Al);
        gld_lds16(Ag + 64 * CC + it * 128, Al + 8192);
        gld_lds16(Bg + it * 128, Bl);
        gld_lds16(Bg + 64 * CC + it * 128, Bl + 8192);
        __syncthreads();  // drains vmcnt(0): staged data visible

#pragma unroll
        for (int ksub = 0; ksub < 4; ksub++) {
            const int c = ksub * 4 + quad;  // 8B k-granule index within BK=128
            long a[2], b[4];
#pragma unroll
            for (int i = 0; i < 2; i++)
                a[i] = *(const long*)&As[(wr + i * 16 + lm) * 128 + (c ^ rsw) * 8];
#pragma unroll
            for (int j = 0; j < 4; j++)
                b[j] = *(const long*)&Bs[(wc + j * 16 + lm) * 128 + (c ^ rsw) * 8];
#pragma unroll
            for (int i = 0; i < 2; i++)
#pragma unroll
                for (int j = 0; j < 4; j++)
                    acc[i][j] = __builtin_amdgcn_mfma_f32_16x16x32_fp8_fp8(a[i], b[j], acc[i][j], 0, 0, 0);
        }
    }

    // C/D layout: col = lm, row = quad*4 + reg (within each 16x16 tile)
    if (MODE == 0) {
#pragma unroll
        for (int j = 0; j < 4; j++) {
            float m = 3.4e38f;
#pragma unroll
            for (int i = 0; i < 2; i++)
#pragma unroll
                for (int e = 0; e < 4; e++)
                    m = fminf(m, (1.0f - acc[i][j][e]) * 0.5f);
            m = fminf(m, __shfl_xor(m, 16));
            m = fminf(m, __shfl_xor(m, 32));
            if (quad == 0) red[wv][j * 16 + lm] = m;  // wave's 32-row min, 64 cols
        }
        __syncthreads();
        if (tid < 128) {
            int grp = tid >> 6, idx = tid & 63;  // grp 0: waves 0-3; grp 1: waves 4-7
            float m = fminf(fminf(red[grp * 4 + 0][idx], red[grp * 4 + 1][idx]),
                            fminf(red[grp * 4 + 2][idx], red[grp * 4 + 3][idx]));
            unsigned u = __float_as_uint(m);
            u = (u & 0x80000000u) ? ~u : (u | 0x80000000u);  // monotone encoding
            atomicMin(&mn_enc[n * PP + p0 + tid], u);
        }
    } else {
#pragma unroll
        for (int j = 0; j < 4; j++) {
            const int col = p0 + wc + j * 16 + lm;  // global p
            unsigned e = mn_enc[n * PP + col];
            unsigned u = (e & 0x80000000u) ? (e & 0x7fffffffu) : ~e;  // decode
            float mnv = __uint_as_float(u);
            // w = exp(10 - 10*raw/(mn+eps)) = exp2(14.4269504 - raw*inv2)
            float inv2 = 14.4269504f / (mnv + 1e-5f);
            float s = 0.f;
#pragma unroll
            for (int i = 0; i < 2; i++)
#pragma unroll
                for (int e2 = 0; e2 < 4; e2++) {
                    float raw = (1.0f - acc[i][j][e2]) * 0.5f;
                    float w = exp2f(fmaf(raw, -inv2, 14.4269504f));
                    s += w;
                    int q = q0 + wr + i * 16 + quad * 4 + e2;  // global q
                    if (q == col) diagw[n * PP + q] = w;       // unique writer
                }
            s += __shfl_xor(s, 16);
            s += __shfl_xor(s, 32);
            if (quad == 0) red[wv][j * 16 + lm] = s;
        }
        __syncthreads();
        if (tid < 128) {
            int grp = tid >> 6, idx = tid & 63;
            float s = red[grp * 4 + 0][idx] + red[grp * 4 + 1][idx] +
                      red[grp * 4 + 2][idx] + red[grp * 4 + 3][idx];
            atomicAdd(&S[n * PP + p0 + tid], s);
        }
    }
}

// ---- kernel 5: loss = mean_n -log(0.5 + 0.5 * mean_q(diagw/S)); n parallel ----
__global__ __launch_bounds__(1024) void finalize_kernel(const float* __restrict__ S,
                                                        const float* __restrict__ diagw,
                                                        float* __restrict__ out) {
    __shared__ float red[1024];
    int tid = threadIdx.x;
    int n = tid >> 9, t = tid & 511;
    float s = 0.f;
    for (int i = t; i < PP; i += 512)
        s += diagw[n * PP + i] / S[n * PP + i];
    red[tid] = s; __syncthreads();
    for (int st = 256; st > 0; st >>= 1) {
        if (t < st) red[n * 512 + t] += red[n * 512 + t + st];
        __syncthreads();
    }
    if (tid == 0) {
        float m0 = 0.5f + 0.5f * (red[0] / (float)PP);
        float m1 = 0.5f + 0.5f * (red[512] / (float)PP);
        out[0] = 0.5f * (-logf(m0) - logf(m1));
    }
}

extern "C" void kernel_launch(void* const* d_in, const int* in_sizes, int n_in,
                              void* d_out, int out_size, void* d_ws, size_t ws_size,
                              hipStream_t stream) {
    const float* I = (const float*)d_in[0];
    const float* T = (const float*)d_in[1];
    float* out = (float*)d_out;

    char* ws = (char*)d_ws;
    const size_t SZ_F8 = (size_t)NN * PP * CC;  // 2 MB each (fp8)
    char* InT = ws;
    char* TnT = ws + SZ_F8;
    float* meanT = (float*)(ws + 2 * SZ_F8);               // 1 KB
    unsigned* mn = (unsigned*)(ws + 2 * SZ_F8 + 32768);    // 32 KB
    float* S = (float*)(ws + 2 * SZ_F8 + 2 * 32768);       // 32 KB
    float* diagw = (float*)(ws + 2 * SZ_F8 + 3 * 32768);   // 32 KB

    mean_kernel<<<CC, 256, 0, stream>>>(T, meanT, mn, S, diagw);
    normalize_kernel<<<dim3(PP / 32, NN, 2), 256, 0, stream>>>(I, T, meanT, InT, TnT);
    cx_gemm<0><<<dim3(PP / 128, PP / 128, NN), 512, 0, stream>>>(TnT, InT, mn, S, diagw);
    cx_gemm<1><<<dim3(PP / 128, PP / 128, NN), 512, 0, stream>>>(TnT, InT, mn, S, diagw);
    finalize_kernel<<<1, 1024, 0, stream>>>(S, diagw, out);
}

// Round 10
// 114.580 us; speedup vs baseline: 3.3405x; 1.1109x over previous
//
#include <hip/hip_runtime.h>
#include <math.h>

#define PP 4096   // P = H*W
#define CC 256    // channels
#define NN 2      // batch

typedef __attribute__((ext_vector_type(4))) float f32x4;

__device__ __forceinline__ void gld_lds16(const char* g, char* l) {
    __builtin_amdgcn_global_load_lds(
        (const __attribute__((address_space(1))) unsigned int*)g,
        (__attribute__((address_space(3))) unsigned int*)l, 16, 0, 0);
}

// ---- kernel 1: meanT[c] = mean over (n,p) of T (float4 loads); init stats ----
__global__ __launch_bounds__(256) void mean_kernel(const float* __restrict__ T,
                                                   float* __restrict__ meanT,
                                                   unsigned* __restrict__ mn_enc,
                                                   float* __restrict__ S,
                                                   float* __restrict__ diagw) {
    int c = blockIdx.x, tid = threadIdx.x;
    float s = 0.f;
    for (int n = 0; n < NN; n++) {
        const float4* Tc = (const float4*)&T[(size_t)(n * CC + c) * PP];
        for (int g = 0; g < 4; g++) {
            float4 v = Tc[tid + g * 256];
            s += (v.x + v.y) + (v.z + v.w);
        }
    }
    __shared__ float red[256];
    red[tid] = s; __syncthreads();
    for (int st = 128; st > 0; st >>= 1) {
        if (tid < st) red[tid] += red[tid + st];
        __syncthreads();
    }
    if (tid == 0) meanT[c] = red[0] * (1.0f / (NN * PP));
    // init stats: 256 blocks x 32 entries = NN*PP = 8192
    int base = blockIdx.x * 32;
    if (tid < 32) {
        mn_enc[base + tid] = 0xFFFFFFFFu;  // +inf in monotone-uint encoding
        S[base + tid] = 0.f;
        diagw[base + tid] = 0.f;
    }
}

// ---- kernel 2: center by meanT, L2-normalize over C, write FP8 e4m3 [n][p][c] ----
// float4 loads over contiguous p; tile pad = 36 floats (144 B rows, 16B aligned).
__global__ __launch_bounds__(256) void normalize_kernel(const float* __restrict__ I,
                                                        const float* __restrict__ T,
                                                        const float* __restrict__ meanT,
                                                        char* __restrict__ InT,
                                                        char* __restrict__ TnT) {
    int pc = blockIdx.x * 32;      // 32 positions per block
    int n = blockIdx.y;
    int which = blockIdx.z;        // 0: I -> InT, 1: T -> TnT
    const float* X = which ? T : I;
    char* Y = which ? TnT : InT;

    __shared__ float tile[CC][36];   // [c][p_local], pad 36 (16B-aligned rows)
    __shared__ float red[32][32];    // [c-group][p_local]
    __shared__ float invn[32];

    int tid = threadIdx.x;
    int pl4 = tid & 7, c0 = tid >> 3;   // 32 c-groups x 8 p-quads
    float sq0 = 0.f, sq1 = 0.f, sq2 = 0.f, sq3 = 0.f;
    for (int c = c0; c < CC; c += 32) {
        float m = meanT[c];
        float4 v = *(const float4*)&X[(size_t)(n * CC + c) * PP + pc + pl4 * 4];
        v.x -= m; v.y -= m; v.z -= m; v.w -= m;
        *(float4*)&tile[c][pl4 * 4] = v;
        sq0 += v.x * v.x; sq1 += v.y * v.y; sq2 += v.z * v.z; sq3 += v.w * v.w;
    }
    red[c0][pl4 * 4 + 0] = sq0;
    red[c0][pl4 * 4 + 1] = sq1;
    red[c0][pl4 * 4 + 2] = sq2;
    red[c0][pl4 * 4 + 3] = sq3;
    __syncthreads();
    if (tid < 32) {
        float s = 0.f;
        for (int k = 0; k < 32; k++) s += red[k][tid];
        invn[tid] = 1.0f / sqrtf(s);
    }
    __syncthreads();
    // write fp8: 4 channels per thread (4B store), 4 rows per pass, 8 passes
    for (int pass = 0; pass < 8; pass++) {
        int r = pass * 4 + (tid >> 6);
        int c4 = (tid & 63) * 4;
        float in = invn[r];
        float v0 = tile[c4 + 0][r] * in;
        float v1 = tile[c4 + 1][r] * in;
        float v2 = tile[c4 + 2][r] * in;
        float v3 = tile[c4 + 3][r] * in;
        int w = __builtin_amdgcn_cvt_pk_fp8_f32(v0, v1, 0, false);
        w = __builtin_amdgcn_cvt_pk_fp8_f32(v2, v3, w, true);
        *(unsigned*)&Y[(size_t)(n * PP + pc + r) * CC + c4] = (unsigned)w;
    }
}

// ---- kernels 3/4: FP8 NT-GEMM dot[q,p] = sum_c TnT[q][c]*InT[p][c] + col stats ----
// (byte-identical to round 9 — validated, absmax 0.0)
// 128x128 tile, BK=128 (two k-iters), 8 waves (32x64 each via 2x4 16x16x32_fp8_fp8
// MFMA, 32 AGPR acc), launch_bounds(512,6), LDS 34 KB. global_load_lds 16B staging.
// Swizzle: stored 16B slot s of row r holds global chunk s^((r>>1)&7); read byte
// pos = (c ^ (lm&14))*8.
// [journal r6/r7: NEVER put device-scope __threadfence in a hot epilogue -
//  L2 writeback storm, 10x. Finalize stays a separate tiny launch.]
// MODE 0: column (over q) min of raw=(1-dot)/2 -> atomicMin(mn_enc) [monotone uint]
// MODE 1: w = exp2(14.427 - raw*inv2); col sum -> atomicAdd(S); diag -> diagw
template <int MODE>
__global__ __launch_bounds__(512, 6) void cx_gemm(const char* __restrict__ TnT,
                                                  const char* __restrict__ InT,
                                                  unsigned* __restrict__ mn_enc,
                                                  float* __restrict__ S,
                                                  float* __restrict__ diagw) {
    const int n = blockIdx.z;
    const char* __restrict__ A = TnT + (size_t)n * PP * CC;  // A[q*CC + c], 1B/elem
    const char* __restrict__ B = InT + (size_t)n * PP * CC;  // B[p*CC + c]
    const int q0 = blockIdx.y * 128, p0 = blockIdx.x * 128;

    __shared__ __align__(16) char As[128 * 128];  // 16 KB
    __shared__ __align__(16) char Bs[128 * 128];  // 16 KB
    __shared__ float red[8][64];                  // 2 KB

    const int tid = threadIdx.x;
    const int l = tid & 63, wv = tid >> 6;
    const int lm = l & 15, quad = l >> 4;
    const int wr = (wv & 3) * 32, wc = (wv >> 2) * 64;  // wave tile: 32 rows x 64 cols

    // staging: issue t covers rows t*64 + (tid>>3), 16B slot tid&7;
    // global chunk16 = slot ^ ((row>>1)&7); LDS dest lane-order contiguous (DMA)
    const int srow = tid >> 3;                        // 0..63
    const int gk = ((tid & 7) ^ ((srow >> 1) & 7)) * 16;  // (row+64)>>1 &7 == same
    const char* Ag = A + (size_t)(q0 + srow) * CC + gk;
    const char* Bg = B + (size_t)(p0 + srow) * CC + gk;
    char* Al = As + tid * 16;
    char* Bl = Bs + tid * 16;

    f32x4 acc[2][4] = {};

    const int rsw = (lm & 14);  // read-side granule XOR (row&14 == lm&14)

#pragma unroll
    for (int it = 0; it < 2; it++) {
        __syncthreads();  // previous iter's LDS reads done
        gld_lds16(Ag + it * 128, Al);
        gld_lds16(Ag + 64 * CC + it * 128, Al + 8192);
        gld_lds16(Bg + it * 128, Bl);
        gld_lds16(Bg + 64 * CC + it * 128, Bl + 8192);
        __syncthreads();  // drains vmcnt(0): staged data visible

#pragma unroll
        for (int ksub = 0; ksub < 4; ksub++) {
            const int c = ksub * 4 + quad;  // 8B k-granule index within BK=128
            long a[2], b[4];
#pragma unroll
            for (int i = 0; i < 2; i++)
                a[i] = *(const long*)&As[(wr + i * 16 + lm) * 128 + (c ^ rsw) * 8];
#pragma unroll
            for (int j = 0; j < 4; j++)
                b[j] = *(const long*)&Bs[(wc + j * 16 + lm) * 128 + (c ^ rsw) * 8];
#pragma unroll
            for (int i = 0; i < 2; i++)
#pragma unroll
                for (int j = 0; j < 4; j++)
                    acc[i][j] = __builtin_amdgcn_mfma_f32_16x16x32_fp8_fp8(a[i], b[j], acc[i][j], 0, 0, 0);
        }
    }

    // C/D layout: col = lm, row = quad*4 + reg (within each 16x16 tile)
    if (MODE == 0) {
#pragma unroll
        for (int j = 0; j < 4; j++) {
            float m = 3.4e38f;
#pragma unroll
            for (int i = 0; i < 2; i++)
#pragma unroll
                for (int e = 0; e < 4; e++)
                    m = fminf(m, (1.0f - acc[i][j][e]) * 0.5f);
            m = fminf(m, __shfl_xor(m, 16));
            m = fminf(m, __shfl_xor(m, 32));
            if (quad == 0) red[wv][j * 16 + lm] = m;  // wave's 32-row min, 64 cols
        }
        __syncthreads();
        if (tid < 128) {
            int grp = tid >> 6, idx = tid & 63;  // grp 0: waves 0-3; grp 1: waves 4-7
            float m = fminf(fminf(red[grp * 4 + 0][idx], red[grp * 4 + 1][idx]),
                            fminf(red[grp * 4 + 2][idx], red[grp * 4 + 3][idx]));
            unsigned u = __float_as_uint(m);
            u = (u & 0x80000000u) ? ~u : (u | 0x80000000u);  // monotone encoding
            atomicMin(&mn_enc[n * PP + p0 + tid], u);
        }
    } else {
#pragma unroll
        for (int j = 0; j < 4; j++) {
            const int col = p0 + wc + j * 16 + lm;  // global p
            unsigned e = mn_enc[n * PP + col];
            unsigned u = (e & 0x80000000u) ? (e & 0x7fffffffu) : ~e;  // decode
            float mnv = __uint_as_float(u);
            // w = exp(10 - 10*raw/(mn+eps)) = exp2(14.4269504 - raw*inv2)
            float inv2 = 14.4269504f / (mnv + 1e-5f);
            float s = 0.f;
#pragma unroll
            for (int i = 0; i < 2; i++)
#pragma unroll
                for (int e2 = 0; e2 < 4; e2++) {
                    float raw = (1.0f - acc[i][j][e2]) * 0.5f;
                    float w = exp2f(fmaf(raw, -inv2, 14.4269504f));
                    s += w;
                    int q = q0 + wr + i * 16 + quad * 4 + e2;  // global q
                    if (q == col) diagw[n * PP + q] = w;       // unique writer
                }
            s += __shfl_xor(s, 16);
            s += __shfl_xor(s, 32);
            if (quad == 0) red[wv][j * 16 + lm] = s;
        }
        __syncthreads();
        if (tid < 128) {
            int grp = tid >> 6, idx = tid & 63;
            float s = red[grp * 4 + 0][idx] + red[grp * 4 + 1][idx] +
                      red[grp * 4 + 2][idx] + red[grp * 4 + 3][idx];
            atomicAdd(&S[n * PP + p0 + tid], s);
        }
    }
}

// ---- kernel 5: loss = mean_n -log(0.5 + 0.5 * mean_q(diagw/S)); float4 loads ----
__global__ __launch_bounds__(1024) void finalize_kernel(const float* __restrict__ S,
                                                        const float* __restrict__ diagw,
                                                        float* __restrict__ out) {
    __shared__ float red[1024];
    int tid = threadIdx.x;
    int n = tid >> 9, t = tid & 511;
    const float4* dv = (const float4*)(diagw + n * PP);
    const float4* sv = (const float4*)(S + n * PP);
    float s = 0.f;
#pragma unroll
    for (int g = 0; g < 2; g++) {
        float4 d = dv[t + g * 512];
        float4 v = sv[t + g * 512];
        s += d.x / v.x + d.y / v.y + d.z / v.z + d.w / v.w;
    }
    red[tid] = s; __syncthreads();
    for (int st = 256; st > 0; st >>= 1) {
        if (t < st) red[n * 512 + t] += red[n * 512 + t + st];
        __syncthreads();
    }
    if (tid == 0) {
        float m0 = 0.5f + 0.5f * (red[0] / (float)PP);
        float m1 = 0.5f + 0.5f * (red[512] / (float)PP);
        out[0] = 0.5f * (-logf(m0) - logf(m1));
    }
}

extern "C" void kernel_launch(void* const* d_in, const int* in_sizes, int n_in,
                              void* d_out, int out_size, void* d_ws, size_t ws_size,
                              hipStream_t stream) {
    const float* I = (const float*)d_in[0];
    const float* T = (const float*)d_in[1];
    float* out = (float*)d_out;

    char* ws = (char*)d_ws;
    const size_t SZ_F8 = (size_t)NN * PP * CC;  // 2 MB each (fp8)
    char* InT = ws;
    char* TnT = ws + SZ_F8;
    float* meanT = (float*)(ws + 2 * SZ_F8);               // 1 KB
    unsigned* mn = (unsigned*)(ws + 2 * SZ_F8 + 32768);    // 32 KB
    float* S = (float*)(ws + 2 * SZ_F8 + 2 * 32768);       // 32 KB
    float* diagw = (float*)(ws + 2 * SZ_F8 + 3 * 32768);   // 32 KB

    mean_kernel<<<CC, 256, 0, stream>>>(T, meanT, mn, S, diagw);
    normalize_kernel<<<dim3(PP / 32, NN, 2), 256, 0, stream>>>(I, T, meanT, InT, TnT);
    cx_gemm<0><<<dim3(PP / 128, PP / 128, NN), 512, 0, stream>>>(TnT, InT, mn, S, diagw);
    cx_gemm<1><<<dim3(PP / 128, PP / 128, NN), 512, 0, stream>>>(TnT, InT, mn, S, diagw);
    finalize_kernel<<<1, 1024, 0, stream>>>(S, diagw, out);
}